// Round 5
// baseline (121.656 us; speedup 1.0000x reference)
//
#include <hip/hip_runtime.h>

#define CH    128
#define HH    56
#define WW    56
#define BB    32
#define NPIX  (BB * HH * WW)   // 100352
#define NSLOT 32
#define PW    66               // padded row width (1 zero col left, 9 right for lane overrun)
#define PH    58               // padded rows
#define PROW  (PW * PH)        // per-batch padded pixels = 3828

struct alignas(16) U2 { unsigned long long x, y; };

// ---------------- pack x signs into zero-padded layout ----------------
// xbp[b][h+1][w+1]; borders stay zero (memset before this kernel).
// bit l of word0 = sign(x[ch 2l]); bit l of word1 = sign(x[ch 2l+1]).
__global__ __launch_bounds__(256) void pack_x_k(const float* __restrict__ x, U2* __restrict__ xbp) {
    int wave = threadIdx.x >> 6;
    int lane = threadIdx.x & 63;
    int p = blockIdx.x * 4 + wave;           // grid = NPIX/4 exactly
    const float2* px = (const float2*)(x + (size_t)p * CH);
    float2 v = px[lane];
    unsigned long long b0 = __ballot(v.x >= 0.0f);
    unsigned long long b1 = __ballot(v.y >= 0.0f);
    if (lane == 0) {
        int w = p % WW;
        int t = p / WW;
        int h = t % HH;
        int b = t / HH;
        U2 o; o.x = b0; o.y = b1;
        xbp[(size_t)b * PROW + (size_t)(h + 1) * PW + (w + 1)] = o;
    }
}

// ---------------- pack W signs, channel-major [co][tap] (+ zero accum) ----------------
__global__ __launch_bounds__(128) void pack_w_k(const float* __restrict__ Wt, U2* __restrict__ wb2,
                                                unsigned long long* __restrict__ accum) {
    int tap = blockIdx.x;     // 0..8
    int co  = threadIdx.x;    // 0..127
    for (int k = tap * 128 + co; k < NSLOT * 256; k += 9 * 128) accum[k] = 0ull;
    const float* base = Wt + (size_t)tap * CH * CH + co;
    unsigned long long b0 = 0, b1 = 0;
    #pragma unroll 4
    for (int ci = 0; ci < 64; ++ci) {
        if (base[(size_t)(2 * ci)     * CH] >= 0.0f) b0 |= 1ull << ci;
        if (base[(size_t)(2 * ci + 1) * CH] >= 0.0f) b1 |= 1ull << ci;
    }
    wb2[co * 9 + tap].x = b0;
    wb2[co * 9 + tap].y = b1;
}

__device__ __forceinline__ int corrv(U2 w) {
    return CH - 2 * (int)(__popcll(w.x) + __popcll(w.y));
}

// ---------------- transposed conv + stats + r store ----------------
// One wave per (h, b) row. lane = pixel w (lanes 56-63 idle/garbage, masked later).
// c-loop: window in VGPRs, weights via scalar loads -> near-pure xor/popcount.
__global__ __launch_bounds__(64) void conv_k(const U2* __restrict__ xbp,
                                             const U2* __restrict__ wb2,
                                             unsigned long long* __restrict__ accum,
                                             unsigned short* __restrict__ rb) {
    __shared__ short y_lds[CH][PW];   // [channel][pixel], pitch 66 shorts: bank-conflict-free
    int h = blockIdx.x;               // 0..55
    int b = blockIdx.y;               // 0..31
    int lane = threadIdx.x;           // pixel w

    // 3x3 window for this lane's pixel: padded rows h..h+2, padded cols lane..lane+2
    const U2* base = xbp + (size_t)b * PROW + (size_t)h * PW + lane;
    U2 X00 = base[0],        X01 = base[1],        X02 = base[2];
    U2 X10 = base[PW],       X11 = base[PW + 1],   X12 = base[PW + 2];
    U2 X20 = base[2 * PW],   X21 = base[2 * PW + 1], X22 = base[2 * PW + 2];

    bool e0 = (h == 0), e2 = (h == HH - 1);

    #pragma unroll 2
    for (int c = 0; c < CH; ++c) {
        const U2* wc = wb2 + c * 9;   // uniform -> s_load
        U2 w0 = wc[0], w1 = wc[1], w2 = wc[2];
        U2 w3 = wc[3], w4 = wc[4], w5 = wc[5];
        U2 w6 = wc[6], w7 = wc[7], w8 = wc[8];
        int base0 = 9 * CH;
        if (e0) base0 -= corrv(w0) + corrv(w1) + corrv(w2);
        if (e2) base0 -= corrv(w6) + corrv(w7) + corrv(w8);
        int m0 = __popcll(X00.x ^ w0.x) + __popcll(X00.y ^ w0.y)
               + __popcll(X01.x ^ w1.x) + __popcll(X01.y ^ w1.y)
               + __popcll(X02.x ^ w2.x) + __popcll(X02.y ^ w2.y);
        int m1 = __popcll(X10.x ^ w3.x) + __popcll(X10.y ^ w3.y)
               + __popcll(X11.x ^ w4.x) + __popcll(X11.y ^ w4.y)
               + __popcll(X12.x ^ w5.x) + __popcll(X12.y ^ w5.y);
        int m2 = __popcll(X20.x ^ w6.x) + __popcll(X20.y ^ w6.y)
               + __popcll(X21.x ^ w7.x) + __popcll(X21.y ^ w7.y)
               + __popcll(X22.x ^ w8.x) + __popcll(X22.y ^ w8.y);
        int y = base0 - 2 * (m0 + m1 + m2);
        y_lds[c][lane] = (short)y;
    }
    __syncthreads();   // single wave: cheap; orders LDS write->read

    // transpose phase: lane = channel (cl0 = lane, cl1 = lane+64)
    int cl0 = lane, cl1 = lane + 64;
    bool v0 = (h > 0), v2 = (h < HH - 1);
    // per-lane column-edge corrections (vector loads, wb2 is L2-hot)
    U2 a0 = wb2[cl0*9+0], a3 = wb2[cl0*9+3], a6 = wb2[cl0*9+6];
    U2 a2 = wb2[cl0*9+2], a5 = wb2[cl0*9+5], a8 = wb2[cl0*9+8];
    U2 b0_ = wb2[cl1*9+0], b3 = wb2[cl1*9+3], b6 = wb2[cl1*9+6];
    U2 b2 = wb2[cl1*9+2], b5 = wb2[cl1*9+5], b8 = wb2[cl1*9+8];
    int cc0a = corrv(a3) + (v0 ? corrv(a0) : 0) + (v2 ? corrv(a6) : 0);
    int cc2a = corrv(a5) + (v0 ? corrv(a2) : 0) + (v2 ? corrv(a8) : 0);
    int cc0b = corrv(b3) + (v0 ? corrv(b0_) : 0) + (v2 ? corrv(b6) : 0);
    int cc2b = corrv(b5) + (v0 ? corrv(b2) : 0) + (v2 ? corrv(b8) : 0);

    unsigned s1a = 0, s2a = 0, s1b = 0, s2b = 0;
    unsigned short* rout = rb + (size_t)(b * HH + h) * WW * CH;

    // p = 0 (peeled: subtract col-0 correction)
    {
        int ya = y_lds[cl0][0] - cc0a;
        int yb = y_lds[cl1][0] - cc0b;
        int ra = ya > 0 ? ya : 0, rv = yb > 0 ? yb : 0;
        s1a += ra; s2a += (unsigned)__mul24(ra, ra);
        s1b += rv; s2b += (unsigned)__mul24(rv, rv);
        rout[cl0] = (unsigned short)ra;
        rout[cl1] = (unsigned short)rv;
    }
    #pragma unroll 2
    for (int p = 1; p < WW - 1; ++p) {
        int ya = y_lds[cl0][p];
        int yb = y_lds[cl1][p];
        int ra = ya > 0 ? ya : 0, rv = yb > 0 ? yb : 0;
        s1a += ra; s2a += (unsigned)__mul24(ra, ra);
        s1b += rv; s2b += (unsigned)__mul24(rv, rv);
        rout[p * CH + cl0] = (unsigned short)ra;
        rout[p * CH + cl1] = (unsigned short)rv;
    }
    // p = 55 (peeled: subtract col-2 correction)
    {
        int ya = y_lds[cl0][WW - 1] - cc2a;
        int yb = y_lds[cl1][WW - 1] - cc2b;
        int ra = ya > 0 ? ya : 0, rv = yb > 0 ? yb : 0;
        s1a += ra; s2a += (unsigned)__mul24(ra, ra);
        s1b += rv; s2b += (unsigned)__mul24(rv, rv);
        rout[(WW - 1) * CH + cl0] = (unsigned short)ra;
        rout[(WW - 1) * CH + cl1] = (unsigned short)rv;
    }

    int slot = (blockIdx.x + blockIdx.y * HH) & (NSLOT - 1);
    atomicAdd(&accum[slot * 256 + cl0],       (unsigned long long)s1a);
    atomicAdd(&accum[slot * 256 + 128 + cl0], (unsigned long long)s2a);
    atomicAdd(&accum[slot * 256 + cl1],       (unsigned long long)s1b);
    atomicAdd(&accum[slot * 256 + 128 + cl1], (unsigned long long)s2b);
}

// ---------------- finalize BN: scale/shift per channel ----------------
__global__ __launch_bounds__(128) void finalize_k(const unsigned long long* __restrict__ accum,
                                                  const float* __restrict__ gamma,
                                                  const float* __restrict__ beta,
                                                  float2* __restrict__ ss) {
    int c = threadIdx.x;
    unsigned long long s1 = 0, s2 = 0;
    #pragma unroll
    for (int s = 0; s < NSLOT; ++s) {
        s1 += accum[s * 256 + c];
        s2 += accum[s * 256 + 128 + c];
    }
    double N    = (double)NPIX;
    double mean = (double)s1 / N;
    double var  = (double)s2 / N - mean * mean;
    double rstd = 1.0 / sqrt(var + 1e-3);
    double sc   = (double)gamma[c] * rstd;
    float2 v;
    v.x = (float)sc;
    v.y = (float)((double)beta[c] - mean * sc);
    ss[c] = v;
}

// ---------------- streaming output: out = r*scale + shift + x ----------------
__global__ __launch_bounds__(256) void out_stream_k(const unsigned short* __restrict__ rb,
                                                    const float2* __restrict__ ss,
                                                    const float* __restrict__ x,
                                                    float* __restrict__ out) {
    int idx4 = blockIdx.x * 256 + threadIdx.x;     // grid covers NPIX*CH/4 exactly
    int c4 = idx4 & (CH / 4 - 1);
    ushort4 r = ((const ushort4*)rb)[idx4];
    float4 xv = ((const float4*)x)[idx4];
    float2 s0 = ss[c4 * 4 + 0], s1 = ss[c4 * 4 + 1];
    float2 s2 = ss[c4 * 4 + 2], s3 = ss[c4 * 4 + 3];
    float4 o;
    o.x = fmaf((float)r.x, s0.x, s0.y + xv.x);
    o.y = fmaf((float)r.y, s1.x, s1.y + xv.y);
    o.z = fmaf((float)r.z, s2.x, s2.y + xv.z);
    o.w = fmaf((float)r.w, s3.x, s3.y + xv.w);
    ((float4*)out)[idx4] = o;
}

extern "C" void kernel_launch(void* const* d_in, const int* in_sizes, int n_in,
                              void* d_out, int out_size, void* d_ws, size_t ws_size,
                              hipStream_t stream) {
    const float* x     = (const float*)d_in[0];
    const float* Wt    = (const float*)d_in[1];
    const float* gamma = (const float*)d_in[2];
    const float* beta  = (const float*)d_in[3];
    float* out = (float*)d_out;

    char* ws = (char*)d_ws;
    const size_t XBP_BYTES = (size_t)BB * PROW * sizeof(U2);        // 1,959,936
    U2* xbp = (U2*)ws;
    U2* wb2 = (U2*)(ws + 1960064);                                  // 18,432 B
    unsigned long long* accum = (unsigned long long*)(ws + 1978496);// 65,536 B
    float2* ss = (float2*)(ws + 2044032);                           // 1,024 B
    unsigned short* rb = (unsigned short*)(ws + 2045056);           // 25,690,112 B

    hipMemsetAsync(xbp, 0, XBP_BYTES, stream);                      // zero padding
    hipLaunchKernelGGL(pack_x_k, dim3(NPIX / 4), dim3(256), 0, stream, x, xbp);
    hipLaunchKernelGGL(pack_w_k, dim3(9),        dim3(128), 0, stream, Wt, wb2, accum);
    hipLaunchKernelGGL(conv_k,   dim3(HH, BB),   dim3(64),  0, stream, xbp, wb2, accum, rb);
    hipLaunchKernelGGL(finalize_k, dim3(1), dim3(128), 0, stream, accum, gamma, beta, ss);
    hipLaunchKernelGGL(out_stream_k, dim3(NPIX * CH / 4 / 256), dim3(256), 0, stream,
                       rb, (const float2*)ss, x, out);
}

// Round 6
// 92.760 us; speedup vs baseline: 1.3115x; 1.3115x over previous
//
#include <hip/hip_runtime.h>

#define CH    128
#define HH    56
#define WW    56
#define BB    32
#define NPIX  (BB * HH * WW)   // 100352
#define NSLOT 32
#define PW    58               // padded row width (1 zero col each side)
#define PROW  (PW * PW)        // padded per-batch pixels = 3364
#define PXT   14               // pixels per thread (4 groups x 14 = 56)

struct alignas(16) U2 { unsigned long long x, y; };

__device__ __forceinline__ int corrv(U2 w) {
    return CH - 2 * (int)(__popcll(w.x) + __popcll(w.y));
}

// ---------------- pack x signs into zero-padded layout ----------------
// xbp[b][h+1][w+1]; borders stay zero (memset before this kernel).
// bit l of word0 = sign(x[ch 2l]); bit l of word1 = sign(x[ch 2l+1]).
__global__ __launch_bounds__(256) void pack_x_k(const float* __restrict__ x, U2* __restrict__ xbp) {
    int wave = threadIdx.x >> 6;
    int lane = threadIdx.x & 63;
    int p = blockIdx.x * 4 + wave;           // grid = NPIX/4 exactly
    const float2* px = (const float2*)(x + (size_t)p * CH);
    float2 v = px[lane];
    unsigned long long b0 = __ballot(v.x >= 0.0f);
    unsigned long long b1 = __ballot(v.y >= 0.0f);
    if (lane == 0) {
        int w = p % WW;
        int t = p / WW;
        int h = t % HH;
        int b = t / HH;
        U2 o; o.x = b0; o.y = b1;
        xbp[(size_t)b * PROW + (size_t)(h + 1) * PW + (w + 1)] = o;
    }
}

// ---------------- pack W signs, tap-major [tap][co] (+ zero accum) ----------------
// W is HWIO: W[kh][kw][ci][co]; even/odd ci split matches pack_x.
__global__ __launch_bounds__(128) void pack_w_k(const float* __restrict__ Wt, U2* __restrict__ wb,
                                                unsigned long long* __restrict__ accum) {
    int tap = blockIdx.x;     // 0..8
    int co  = threadIdx.x;    // 0..127
    for (int k = tap * 128 + co; k < NSLOT * 256; k += 9 * 128) accum[k] = 0ull;
    const float* base = Wt + (size_t)tap * CH * CH + co;
    unsigned long long b0 = 0, b1 = 0;
    #pragma unroll 4
    for (int ci = 0; ci < 64; ++ci) {
        if (base[(size_t)(2 * ci)     * CH] >= 0.0f) b0 |= 1ull << ci;
        if (base[(size_t)(2 * ci + 1) * CH] >= 0.0f) b1 |= 1ull << ci;
    }
    wb[tap * CH + co].x = b0;
    wb[tap * CH + co].y = b1;
}

// ---------------- conv + stats, 2 channels per thread ----------------
// Block = (h, b). 256 threads: cp = tid&63 -> channels {2cp, 2cp+1};
// g = tid>>6 -> pixel group of 14. Window regs shared by both channels;
// r pair packed into one u32 store (lane=cp -> coalesced).
__global__ __launch_bounds__(256) void conv_stats_k(const U2* __restrict__ xbp,
                                                    const U2* __restrict__ wbg,
                                                    unsigned long long* __restrict__ accum,
                                                    unsigned short* __restrict__ rb) {
    int h = blockIdx.x;       // 0..55
    int b = blockIdx.y;       // 0..31
    int tid = threadIdx.x;
    int cp = tid & 63;
    int g  = tid >> 6;
    int c0 = cp * 2;

    // per-thread weights for the channel pair
    U2 wa[9], wc[9];
    #pragma unroll
    for (int t = 0; t < 9; ++t) {
        wa[t] = wbg[t * CH + c0];
        wc[t] = wbg[t * CH + c0 + 1];
    }
    int ca[9], cb[9];
    #pragma unroll
    for (int t = 0; t < 9; ++t) { ca[t] = corrv(wa[t]); cb[t] = corrv(wc[t]); }

    bool e0 = (h == 0), e2 = (h == HH - 1);
    int basea = 9 * CH, baseb = 9 * CH;
    if (e0) { basea -= ca[0] + ca[1] + ca[2]; baseb -= cb[0] + cb[1] + cb[2]; }
    if (e2) { basea -= ca[6] + ca[7] + ca[8]; baseb -= cb[6] + cb[7] + cb[8]; }
    int ccol0a = ca[3] + (!e0 ? ca[0] : 0) + (!e2 ? ca[6] : 0);
    int ccol2a = ca[5] + (!e0 ? ca[2] : 0) + (!e2 ? ca[8] : 0);
    int ccol0b = cb[3] + (!e0 ? cb[0] : 0) + (!e2 ? cb[6] : 0);
    int ccol2b = cb[5] + (!e0 ? cb[2] : 0) + (!e2 ? cb[8] : 0);

    int w0 = g * PXT;
    // padded rows h..h+2 = image rows h-1..h+1; padded col w0 = image col w0-1
    const U2* r0 = xbp + (size_t)b * PROW + (size_t)h * PW + w0;
    const U2* r1 = r0 + PW;
    const U2* r2 = r1 + PW;

    U2 A0 = r0[0], A1 = r1[0], A2 = r2[0];
    U2 B0 = r0[1], B1 = r1[1], B2 = r2[1];

    unsigned s1a = 0, s2a = 0, s1b = 0, s2b = 0;
    unsigned int* rout = (unsigned int*)(rb + ((((size_t)b * HH + h) * WW) + w0) * CH + c0);

    #pragma unroll
    for (int i = 0; i < PXT; ++i) {
        U2 C0 = r0[i + 2], C1 = r1[i + 2], C2 = r2[i + 2];
        // channel a: 3 row-chains for ILP
        int a0 = __popcll(A0.x ^ wa[0].x) + __popcll(A0.y ^ wa[0].y)
               + __popcll(B0.x ^ wa[1].x) + __popcll(B0.y ^ wa[1].y)
               + __popcll(C0.x ^ wa[2].x) + __popcll(C0.y ^ wa[2].y);
        int a1 = __popcll(A1.x ^ wa[3].x) + __popcll(A1.y ^ wa[3].y)
               + __popcll(B1.x ^ wa[4].x) + __popcll(B1.y ^ wa[4].y)
               + __popcll(C1.x ^ wa[5].x) + __popcll(C1.y ^ wa[5].y);
        int a2 = __popcll(A2.x ^ wa[6].x) + __popcll(A2.y ^ wa[6].y)
               + __popcll(B2.x ^ wa[7].x) + __popcll(B2.y ^ wa[7].y)
               + __popcll(C2.x ^ wa[8].x) + __popcll(C2.y ^ wa[8].y);
        // channel b
        int b0 = __popcll(A0.x ^ wc[0].x) + __popcll(A0.y ^ wc[0].y)
               + __popcll(B0.x ^ wc[1].x) + __popcll(B0.y ^ wc[1].y)
               + __popcll(C0.x ^ wc[2].x) + __popcll(C0.y ^ wc[2].y);
        int b1 = __popcll(A1.x ^ wc[3].x) + __popcll(A1.y ^ wc[3].y)
               + __popcll(B1.x ^ wc[4].x) + __popcll(B1.y ^ wc[4].y)
               + __popcll(C1.x ^ wc[5].x) + __popcll(C1.y ^ wc[5].y);
        int b2 = __popcll(A2.x ^ wc[6].x) + __popcll(A2.y ^ wc[6].y)
               + __popcll(B2.x ^ wc[7].x) + __popcll(B2.y ^ wc[7].y)
               + __popcll(C2.x ^ wc[8].x) + __popcll(C2.y ^ wc[8].y);

        int ya = basea - 2 * (a0 + a1 + a2);
        int yb = baseb - 2 * (b0 + b1 + b2);
        if (i == 0       && g == 0) { ya -= ccol0a; yb -= ccol0b; }   // w == 0
        if (i == PXT - 1 && g == 3) { ya -= ccol2a; yb -= ccol2b; }   // w == 55
        int ra = ya > 0 ? ya : 0;
        int rc = yb > 0 ? yb : 0;
        s1a += (unsigned)ra; s2a += (unsigned)__mul24(ra, ra);
        s1b += (unsigned)rc; s2b += (unsigned)__mul24(rc, rc);
        rout[i * (CH / 2)] = (unsigned)ra | ((unsigned)rc << 16);
        A0 = B0; A1 = B1; A2 = B2;
        B0 = C0; B1 = C1; B2 = C2;
    }

    int slot = (blockIdx.x + blockIdx.y * HH) & (NSLOT - 1);
    atomicAdd(&accum[slot * 256 + c0],           (unsigned long long)s1a);
    atomicAdd(&accum[slot * 256 + 128 + c0],     (unsigned long long)s2a);
    atomicAdd(&accum[slot * 256 + c0 + 1],       (unsigned long long)s1b);
    atomicAdd(&accum[slot * 256 + 128 + c0 + 1], (unsigned long long)s2b);
}

// ---------------- finalize BN: scale/shift per channel ----------------
__global__ __launch_bounds__(128) void finalize_k(const unsigned long long* __restrict__ accum,
                                                  const float* __restrict__ gamma,
                                                  const float* __restrict__ beta,
                                                  float2* __restrict__ ss) {
    int c = threadIdx.x;
    unsigned long long s1 = 0, s2 = 0;
    #pragma unroll
    for (int s = 0; s < NSLOT; ++s) {
        s1 += accum[s * 256 + c];
        s2 += accum[s * 256 + 128 + c];
    }
    double N    = (double)NPIX;
    double mean = (double)s1 / N;
    double var  = (double)s2 / N - mean * mean;
    double rstd = 1.0 / sqrt(var + 1e-3);
    double sc   = (double)gamma[c] * rstd;
    float2 v;
    v.x = (float)sc;
    v.y = (float)((double)beta[c] - mean * sc);
    ss[c] = v;
}

// ---------------- streaming output: out = r*scale + shift + x ----------------
__global__ __launch_bounds__(256) void out_stream_k(const unsigned short* __restrict__ rb,
                                                    const float2* __restrict__ ss,
                                                    const float* __restrict__ x,
                                                    float* __restrict__ out) {
    int idx4 = blockIdx.x * 256 + threadIdx.x;     // grid covers NPIX*CH/4 exactly
    int c4 = idx4 & (CH / 4 - 1);
    ushort4 r = ((const ushort4*)rb)[idx4];
    float4 xv = ((const float4*)x)[idx4];
    float2 s0 = ss[c4 * 4 + 0], s1 = ss[c4 * 4 + 1];
    float2 s2 = ss[c4 * 4 + 2], s3 = ss[c4 * 4 + 3];
    float4 o;
    o.x = fmaf((float)r.x, s0.x, s0.y + xv.x);
    o.y = fmaf((float)r.y, s1.x, s1.y + xv.y);
    o.z = fmaf((float)r.z, s2.x, s2.y + xv.z);
    o.w = fmaf((float)r.w, s3.x, s3.y + xv.w);
    ((float4*)out)[idx4] = o;
}

extern "C" void kernel_launch(void* const* d_in, const int* in_sizes, int n_in,
                              void* d_out, int out_size, void* d_ws, size_t ws_size,
                              hipStream_t stream) {
    const float* x     = (const float*)d_in[0];
    const float* Wt    = (const float*)d_in[1];
    const float* gamma = (const float*)d_in[2];
    const float* beta  = (const float*)d_in[3];
    float* out = (float*)d_out;

    char* ws = (char*)d_ws;
    const size_t XBP_BYTES = (size_t)BB * PROW * sizeof(U2);        // 1,722,368
    U2* xbp = (U2*)ws;
    U2* wb  = (U2*)(ws + 1722368);                                  // 18,432 B
    unsigned long long* accum = (unsigned long long*)(ws + 1740800);// 65,536 B
    float2* ss = (float2*)(ws + 1806336);                           // 1,024 B
    unsigned short* rb = (unsigned short*)(ws + 1807360);           // 25,690,112 B

    hipMemsetAsync(xbp, 0, XBP_BYTES, stream);                      // zero padding
    hipLaunchKernelGGL(pack_x_k, dim3(NPIX / 4), dim3(256), 0, stream, x, xbp);
    hipLaunchKernelGGL(pack_w_k, dim3(9),        dim3(128), 0, stream, Wt, wb, accum);
    hipLaunchKernelGGL(conv_stats_k, dim3(HH, BB), dim3(256), 0, stream, xbp, wb, accum, rb);
    hipLaunchKernelGGL(finalize_k, dim3(1), dim3(128), 0, stream, accum, gamma, beta, ss);
    hipLaunchKernelGGL(out_stream_k, dim3(NPIX * CH / 4 / 256), dim3(256), 0, stream,
                       rb, (const float2*)ss, x, out);
}

// Round 8
// 84.411 us; speedup vs baseline: 1.4412x; 1.0989x over previous
//
#include <hip/hip_runtime.h>

#define CH    128
#define HH    56
#define WW    56
#define BB    32
#define NPIX  (BB * HH * WW)   // 100352
#define NSLOT 32
#define PW    58               // padded row width (1 zero col each side)
#define PROW  (PW * PW)        // padded per-batch pixels = 3364

struct alignas(16) U2 { unsigned long long x, y; };

__device__ __forceinline__ int corrv(U2 w) {
    return CH - 2 * (int)(__popcll(w.x) + __popcll(w.y));
}

// xor + chained popcount of one 64-bit word vs weight word: exactly 4 VALU ops.
// acc' = acc + popc(lo(a)^lo(w)) + popc(hi(a)^hi(w))
__device__ __forceinline__ unsigned xp0(unsigned long long a, unsigned long long w) {
    unsigned acc, t0, t1;
    asm("v_xor_b32 %1, %3, %5\n\t"
        "v_xor_b32 %2, %4, %6\n\t"
        "v_bcnt_u32_b32 %0, %1, 0\n\t"
        "v_bcnt_u32_b32 %0, %2, %0"
        : "=&v"(acc), "=&v"(t0), "=&v"(t1)
        : "v"((unsigned)a), "v"((unsigned)(a >> 32)),
          "v"((unsigned)w), "v"((unsigned)(w >> 32)));
    return acc;
}
__device__ __forceinline__ unsigned xp(unsigned acc, unsigned long long a, unsigned long long w) {
    unsigned t0, t1;
    asm("v_xor_b32 %1, %3, %5\n\t"
        "v_xor_b32 %2, %4, %6\n\t"
        "v_bcnt_u32_b32 %0, %1, %0\n\t"
        "v_bcnt_u32_b32 %0, %2, %0"
        : "+v"(acc), "=&v"(t0), "=&v"(t1)
        : "v"((unsigned)a), "v"((unsigned)(a >> 32)),
          "v"((unsigned)w), "v"((unsigned)(w >> 32)));
    return acc;
}

// mismatch count of one window row (3 taps) against one channel's weight row
__device__ __forceinline__ unsigned row_mis(const U2& A, const U2& B, const U2& C,
                                            const U2& w0, const U2& w1, const U2& w2) {
    unsigned m = xp0(A.x, w0.x);
    m = xp(m, A.y, w0.y);
    m = xp(m, B.x, w1.x);
    m = xp(m, B.y, w1.y);
    m = xp(m, C.x, w2.x);
    m = xp(m, C.y, w2.y);
    return m;
}

// ---------------- pack x signs into zero-padded layout ----------------
// xbp[b][h+1][w+1]; borders stay zero (memset before this kernel).
// bit l of word0 = sign(x[ch 2l]); bit l of word1 = sign(x[ch 2l+1]).
__global__ __launch_bounds__(256) void pack_x_k(const float* __restrict__ x, U2* __restrict__ xbp) {
    int wave = threadIdx.x >> 6;
    int lane = threadIdx.x & 63;
    int p = blockIdx.x * 4 + wave;           // grid = NPIX/4 exactly
    const float2* px = (const float2*)(x + (size_t)p * CH);
    float2 v = px[lane];
    unsigned long long b0 = __ballot(v.x >= 0.0f);
    unsigned long long b1 = __ballot(v.y >= 0.0f);
    if (lane == 0) {
        int w = p % WW;
        int t = p / WW;
        int h = t % HH;
        int b = t / HH;
        U2 o; o.x = b0; o.y = b1;
        xbp[(size_t)b * PROW + (size_t)(h + 1) * PW + (w + 1)] = o;
    }
}

// ---------------- pack W signs, tap-major [tap][co] (+ zero accum) ----------------
// W is HWIO: W[kh][kw][ci][co]; even/odd ci split matches pack_x.
__global__ __launch_bounds__(128) void pack_w_k(const float* __restrict__ Wt, U2* __restrict__ wb,
                                                unsigned long long* __restrict__ accum) {
    int tap = blockIdx.x;     // 0..8
    int co  = threadIdx.x;    // 0..127
    for (int k = tap * 128 + co; k < NSLOT * 256; k += 9 * 128) accum[k] = 0ull;
    const float* base = Wt + (size_t)tap * CH * CH + co;
    unsigned long long b0 = 0, b1 = 0;
    #pragma unroll 4
    for (int ci = 0; ci < 64; ++ci) {
        if (base[(size_t)(2 * ci)     * CH] >= 0.0f) b0 |= 1ull << ci;
        if (base[(size_t)(2 * ci + 1) * CH] >= 0.0f) b1 |= 1ull << ci;
    }
    wb[tap * CH + co].x = b0;
    wb[tap * CH + co].y = b1;
}

// ---------------- conv + stats (stores r as u16) ----------------
// Block = (h, b). 256 threads: c = tid&127, g = tid>>7 (column half, 28 cols).
// Sliding window in VGPRs; weights pinned in VGPRs by asm constraints.
__global__ __launch_bounds__(256) void conv_stats_k(const U2* __restrict__ xbp,
                                                    const U2* __restrict__ wbg,
                                                    unsigned long long* __restrict__ accum,
                                                    unsigned short* __restrict__ rb) {
    int h = blockIdx.x;       // 0..55
    int b = blockIdx.y;       // 0..31
    int tid = threadIdx.x;
    int c = tid & (CH - 1);
    int g = tid >> 7;

    U2 wk[9];
    int co[9];
    #pragma unroll
    for (int t = 0; t < 9; ++t) { wk[t] = wbg[t * CH + c]; co[t] = corrv(wk[t]); }

    bool e0 = (h == 0), e2 = (h == HH - 1);
    int base0 = 9 * CH;
    if (e0) base0 -= co[0] + co[1] + co[2];
    if (e2) base0 -= co[6] + co[7] + co[8];
    int ccol0 = co[3] + (!e0 ? co[0] : 0) + (!e2 ? co[6] : 0);
    int ccol2 = co[5] + (!e0 ? co[2] : 0) + (!e2 ? co[8] : 0);

    int w0 = g * 28;
    // padded rows h..h+2 = image rows h-1..h+1; padded col w0 = image col w0-1
    const U2* r0 = xbp + (size_t)b * PROW + (size_t)h * PW + w0;
    const U2* r1 = r0 + PW;
    const U2* r2 = r1 + PW;

    U2 A0 = r0[0], A1 = r1[0], A2 = r2[0];
    U2 B0 = r0[1], B1 = r1[1], B2 = r2[1];

    unsigned s1 = 0, s2 = 0;
    unsigned short* rout = rb + ((((size_t)b * HH + h) * WW) + w0) * CH + c;

    #pragma unroll
    for (int i = 0; i < 28; ++i) {
        U2 C0 = r0[i + 2], C1 = r1[i + 2], C2 = r2[i + 2];
        unsigned m0 = row_mis(A0, B0, C0, wk[0], wk[1], wk[2]);
        unsigned m1 = row_mis(A1, B1, C1, wk[3], wk[4], wk[5]);
        unsigned m2 = row_mis(A2, B2, C2, wk[6], wk[7], wk[8]);
        int y = base0 - 2 * (int)(m0 + m1 + m2);
        if (i == 0  && g == 0) y -= ccol0;   // w == 0
        if (i == 27 && g == 1) y -= ccol2;   // w == 55
        int r = y > 0 ? y : 0;
        s1 += (unsigned)r;
        s2 += (unsigned)__mul24(r, r);       // r <= 1152 -> exact, full-rate
        rout[(size_t)i * CH] = (unsigned short)r;
        A0 = B0; A1 = B1; A2 = B2;
        B0 = C0; B1 = C1; B2 = C2;
    }

    int slot = (blockIdx.x + blockIdx.y * HH) & (NSLOT - 1);
    atomicAdd(&accum[slot * 256 + c],       (unsigned long long)s1);
    atomicAdd(&accum[slot * 256 + 128 + c], (unsigned long long)s2);
}

// ---------------- finalize BN: scale/shift per channel ----------------
__global__ __launch_bounds__(128) void finalize_k(const unsigned long long* __restrict__ accum,
                                                  const float* __restrict__ gamma,
                                                  const float* __restrict__ beta,
                                                  float2* __restrict__ ss) {
    int c = threadIdx.x;
    unsigned long long s1 = 0, s2 = 0;
    #pragma unroll
    for (int s = 0; s < NSLOT; ++s) {
        s1 += accum[s * 256 + c];
        s2 += accum[s * 256 + 128 + c];
    }
    double N    = (double)NPIX;
    double mean = (double)s1 / N;
    double var  = (double)s2 / N - mean * mean;
    double rstd = 1.0 / sqrt(var + 1e-3);
    double sc   = (double)gamma[c] * rstd;
    float2 v;
    v.x = (float)sc;
    v.y = (float)((double)beta[c] - mean * sc);
    ss[c] = v;
}

// ---------------- streaming output: out = r*scale + shift + x ----------------
__global__ __launch_bounds__(256) void out_stream_k(const unsigned short* __restrict__ rb,
                                                    const float2* __restrict__ ss,
                                                    const float* __restrict__ x,
                                                    float* __restrict__ out) {
    int idx4 = blockIdx.x * 256 + threadIdx.x;     // grid covers NPIX*CH/4 exactly
    int c4 = idx4 & (CH / 4 - 1);
    ushort4 r = ((const ushort4*)rb)[idx4];
    float4 xv = ((const float4*)x)[idx4];
    float2 s0 = ss[c4 * 4 + 0], s1 = ss[c4 * 4 + 1];
    float2 s2 = ss[c4 * 4 + 2], s3 = ss[c4 * 4 + 3];
    float4 o;
    o.x = fmaf((float)r.x, s0.x, s0.y + xv.x);
    o.y = fmaf((float)r.y, s1.x, s1.y + xv.y);
    o.z = fmaf((float)r.z, s2.x, s2.y + xv.z);
    o.w = fmaf((float)r.w, s3.x, s3.y + xv.w);
    ((float4*)out)[idx4] = o;
}

extern "C" void kernel_launch(void* const* d_in, const int* in_sizes, int n_in,
                              void* d_out, int out_size, void* d_ws, size_t ws_size,
                              hipStream_t stream) {
    const float* x     = (const float*)d_in[0];
    const float* Wt    = (const float*)d_in[1];
    const float* gamma = (const float*)d_in[2];
    const float* beta  = (const float*)d_in[3];
    float* out = (float*)d_out;

    char* ws = (char*)d_ws;
    const size_t XBP_BYTES = (size_t)BB * PROW * sizeof(U2);        // 1,722,368
    U2* xbp = (U2*)ws;
    U2* wb  = (U2*)(ws + 1722368);                                  // 18,432 B
    unsigned long long* accum = (unsigned long long*)(ws + 1740800);// 65,536 B
    float2* ss = (float2*)(ws + 1806336);                           // 1,024 B
    unsigned short* rb = (unsigned short*)(ws + 1807360);           // 25,690,112 B

    hipMemsetAsync(xbp, 0, XBP_BYTES, stream);                      // zero padding
    hipLaunchKernelGGL(pack_x_k, dim3(NPIX / 4), dim3(256), 0, stream, x, xbp);
    hipLaunchKernelGGL(pack_w_k, dim3(9),        dim3(128), 0, stream, Wt, wb, accum);
    hipLaunchKernelGGL(conv_stats_k, dim3(HH, BB), dim3(256), 0, stream, xbp, wb, accum, rb);
    hipLaunchKernelGGL(finalize_k, dim3(1), dim3(128), 0, stream, accum, gamma, beta, ss);
    hipLaunchKernelGGL(out_stream_k, dim3(NPIX * CH / 4 / 256), dim3(256), 0, stream,
                       rb, (const float2*)ss, x, out);
}

// Round 9
// 80.925 us; speedup vs baseline: 1.5033x; 1.0431x over previous
//
#include <hip/hip_runtime.h>

#define CH    128
#define HH    56
#define WW    56
#define BB    32
#define NPIX  (BB * HH * WW)   // 100352
#define NSLOT 16
#define PW    58               // padded row width (1 zero col each side)
#define PROW  (PW * PW)        // padded per-batch pixels = 3364
#define HP    28               // row pairs

struct alignas(16) U2 { unsigned long long x, y; };

__device__ __forceinline__ int corrv(U2 w) {
    return CH - 2 * (int)(__popcll(w.x) + __popcll(w.y));
}

// xor + chained popcount of one 64-bit word vs weight word: exactly 4 VALU ops.
__device__ __forceinline__ unsigned xp0(unsigned long long a, unsigned long long w) {
    unsigned acc, t0, t1;
    asm("v_xor_b32 %1, %3, %5\n\t"
        "v_xor_b32 %2, %4, %6\n\t"
        "v_bcnt_u32_b32 %0, %1, 0\n\t"
        "v_bcnt_u32_b32 %0, %2, %0"
        : "=&v"(acc), "=&v"(t0), "=&v"(t1)
        : "v"((unsigned)a), "v"((unsigned)(a >> 32)),
          "v"((unsigned)w), "v"((unsigned)(w >> 32)));
    return acc;
}
__device__ __forceinline__ unsigned xp(unsigned acc, unsigned long long a, unsigned long long w) {
    unsigned t0, t1;
    asm("v_xor_b32 %1, %3, %5\n\t"
        "v_xor_b32 %2, %4, %6\n\t"
        "v_bcnt_u32_b32 %0, %1, %0\n\t"
        "v_bcnt_u32_b32 %0, %2, %0"
        : "+v"(acc), "=&v"(t0), "=&v"(t1)
        : "v"((unsigned)a), "v"((unsigned)(a >> 32)),
          "v"((unsigned)w), "v"((unsigned)(w >> 32)));
    return acc;
}

// mismatch count of one window row (3 taps) against one channel's weight row
__device__ __forceinline__ unsigned row_mis(const U2& A, const U2& B, const U2& C,
                                            const U2& w0, const U2& w1, const U2& w2) {
    unsigned m = xp0(A.x, w0.x);
    m = xp(m, A.y, w0.y);
    m = xp(m, B.x, w1.x);
    m = xp(m, B.y, w1.y);
    m = xp(m, C.x, w2.x);
    m = xp(m, C.y, w2.y);
    return m;
}

// ---------------- pack x signs into zero-padded layout (interior only) ----------------
__global__ __launch_bounds__(256) void pack_x_k(const float* __restrict__ x, U2* __restrict__ xbp) {
    int wave = threadIdx.x >> 6;
    int lane = threadIdx.x & 63;
    int p = blockIdx.x * 4 + wave;           // grid = NPIX/4 exactly
    const float2* px = (const float2*)(x + (size_t)p * CH);
    float2 v = px[lane];
    unsigned long long b0 = __ballot(v.x >= 0.0f);
    unsigned long long b1 = __ballot(v.y >= 0.0f);
    if (lane == 0) {
        int w = p % WW;
        int t = p / WW;
        int h = t % HH;
        int b = t / HH;
        U2 o; o.x = b0; o.y = b1;
        xbp[(size_t)b * PROW + (size_t)(h + 1) * PW + (w + 1)] = o;
    }
}

// ---------------- pack W signs + zero accum + zero xbp borders ----------------
// W is HWIO: W[kh][kw][ci][co]; even/odd ci split matches pack_x.
// Border writes are disjoint from pack_x's interior writes -> order-independent.
__global__ __launch_bounds__(128) void pack_w_k(const float* __restrict__ Wt, U2* __restrict__ wb,
                                                unsigned long long* __restrict__ accum,
                                                U2* __restrict__ xbp) {
    int tap = blockIdx.x;     // 0..8
    int co  = threadIdx.x;    // 0..127
    int gtid = tap * 128 + co;
    for (int k = gtid; k < NSLOT * 256; k += 9 * 128) accum[k] = 0ull;
    U2 z; z.x = 0ull; z.y = 0ull;
    for (int k = gtid; k < BB * 228; k += 9 * 128) {   // 228 border cells per batch
        int bb = k / 228, e = k % 228;
        int row, col;
        if (e < 58)       { row = 0;       col = e; }
        else if (e < 116) { row = 57;      col = e - 58; }
        else if (e < 172) { row = e - 115; col = 0; }    // rows 1..56
        else              { row = e - 171; col = 57; }   // rows 1..56
        xbp[(size_t)bb * PROW + (size_t)row * PW + col] = z;
    }
    const float* base = Wt + (size_t)tap * CH * CH + co;
    unsigned long long b0 = 0, b1 = 0;
    #pragma unroll 4
    for (int ci = 0; ci < 64; ++ci) {
        if (base[(size_t)(2 * ci)     * CH] >= 0.0f) b0 |= 1ull << ci;
        if (base[(size_t)(2 * ci + 1) * CH] >= 0.0f) b1 |= 1ull << ci;
    }
    wb[tap * CH + co].x = b0;
    wb[tap * CH + co].y = b1;
}

// ---------------- conv + stats, 2 output rows per thread ----------------
// Block = (hp, b): output rows 2hp, 2hp+1. 256 threads: c = tid&127,
// g = tid>>7 (column half, 28 cols). 4-row sliding window serves both outputs.
__global__ __launch_bounds__(256) void conv_stats_k(const U2* __restrict__ xbp,
                                                    const U2* __restrict__ wbg,
                                                    unsigned long long* __restrict__ accum,
                                                    unsigned short* __restrict__ rb) {
    int hp = blockIdx.x;      // 0..27
    int b  = blockIdx.y;      // 0..31
    int tid = threadIdx.x;
    int c = tid & (CH - 1);
    int g = tid >> 7;
    int rowA = 2 * hp;        // top output row (never 55)
    // rowB = rowA + 1 (never 0)

    U2 wk[9];
    int co[9];
    #pragma unroll
    for (int t = 0; t < 9; ++t) { wk[t] = wbg[t * CH + c]; co[t] = corrv(wk[t]); }

    bool e0 = (hp == 0);       // rowA == 0
    bool e2 = (hp == HP - 1);  // rowB == 55
    int baseA = 9 * CH, baseB = 9 * CH;
    if (e0) baseA -= co[0] + co[1] + co[2];
    if (e2) baseB -= co[6] + co[7] + co[8];
    int ccol0A = co[3] + (!e0 ? co[0] : 0) + co[6];
    int ccol2A = co[5] + (!e0 ? co[2] : 0) + co[8];
    int ccol0B = co[3] + co[0] + (!e2 ? co[6] : 0);
    int ccol2B = co[5] + co[2] + (!e2 ? co[8] : 0);

    int w0 = g * 28;
    // padded rows rowA..rowA+3 = image rows rowA-1..rowA+2
    const U2* q0 = xbp + (size_t)b * PROW + (size_t)rowA * PW + w0;
    const U2* q1 = q0 + PW;
    const U2* q2 = q1 + PW;
    const U2* q3 = q2 + PW;

    U2 A0 = q0[0], A1 = q1[0], A2 = q2[0], A3 = q3[0];
    U2 B0 = q0[1], B1 = q1[1], B2 = q2[1], B3 = q3[1];

    unsigned s1 = 0, s2 = 0;
    unsigned short* routA = rb + ((((size_t)b * HH + rowA) * WW) + w0) * CH + c;
    unsigned short* routB = routA + (size_t)WW * CH;

    #pragma unroll 14
    for (int i = 0; i < 28; ++i) {
        U2 C0 = q0[i + 2], C1 = q1[i + 2], C2 = q2[i + 2], C3 = q3[i + 2];
        // output row A: window rows 0..2
        unsigned mA0 = row_mis(A0, B0, C0, wk[0], wk[1], wk[2]);
        unsigned mA1 = row_mis(A1, B1, C1, wk[3], wk[4], wk[5]);
        unsigned mA2 = row_mis(A2, B2, C2, wk[6], wk[7], wk[8]);
        // output row B: window rows 1..3
        unsigned mB0 = row_mis(A1, B1, C1, wk[0], wk[1], wk[2]);
        unsigned mB1 = row_mis(A2, B2, C2, wk[3], wk[4], wk[5]);
        unsigned mB2 = row_mis(A3, B3, C3, wk[6], wk[7], wk[8]);
        int yA = baseA - 2 * (int)(mA0 + mA1 + mA2);
        int yB = baseB - 2 * (int)(mB0 + mB1 + mB2);
        if (i == 0  && g == 0) { yA -= ccol0A; yB -= ccol0B; }   // w == 0
        if (i == 27 && g == 1) { yA -= ccol2A; yB -= ccol2B; }   // w == 55
        int ra = yA > 0 ? yA : 0;
        int rv = yB > 0 ? yB : 0;
        s1 += (unsigned)(ra + rv);
        s2 += (unsigned)__mul24(ra, ra) + (unsigned)__mul24(rv, rv);
        routA[(size_t)i * CH] = (unsigned short)ra;
        routB[(size_t)i * CH] = (unsigned short)rv;
        A0 = B0; A1 = B1; A2 = B2; A3 = B3;
        B0 = C0; B1 = C1; B2 = C2; B3 = C3;
    }

    int slot = (hp + b * HP) & (NSLOT - 1);
    atomicAdd(&accum[slot * 256 + c],       (unsigned long long)s1);
    atomicAdd(&accum[slot * 256 + 128 + c], (unsigned long long)s2);
}

// ---------------- finalize BN: scale/shift per channel ----------------
__global__ __launch_bounds__(128) void finalize_k(const unsigned long long* __restrict__ accum,
                                                  const float* __restrict__ gamma,
                                                  const float* __restrict__ beta,
                                                  float2* __restrict__ ss) {
    int c = threadIdx.x;
    unsigned long long s1 = 0, s2 = 0;
    #pragma unroll
    for (int s = 0; s < NSLOT; ++s) {
        s1 += accum[s * 256 + c];
        s2 += accum[s * 256 + 128 + c];
    }
    double N    = (double)NPIX;
    double mean = (double)s1 / N;
    double var  = (double)s2 / N - mean * mean;
    double rstd = 1.0 / sqrt(var + 1e-3);
    double sc   = (double)gamma[c] * rstd;
    float2 v;
    v.x = (float)sc;
    v.y = (float)((double)beta[c] - mean * sc);
    ss[c] = v;
}

// ---------------- streaming output: out = r*scale + shift + x ----------------
__global__ __launch_bounds__(256) void out_stream_k(const unsigned short* __restrict__ rb,
                                                    const float2* __restrict__ ss,
                                                    const float* __restrict__ x,
                                                    float* __restrict__ out) {
    int idx4 = blockIdx.x * 256 + threadIdx.x;     // grid covers NPIX*CH/4 exactly
    int c4 = idx4 & (CH / 4 - 1);
    ushort4 r = ((const ushort4*)rb)[idx4];
    float4 xv = ((const float4*)x)[idx4];
    float2 s0 = ss[c4 * 4 + 0], s1 = ss[c4 * 4 + 1];
    float2 s2 = ss[c4 * 4 + 2], s3 = ss[c4 * 4 + 3];
    float4 o;
    o.x = fmaf((float)r.x, s0.x, s0.y + xv.x);
    o.y = fmaf((float)r.y, s1.x, s1.y + xv.y);
    o.z = fmaf((float)r.z, s2.x, s2.y + xv.z);
    o.w = fmaf((float)r.w, s3.x, s3.y + xv.w);
    ((float4*)out)[idx4] = o;
}

extern "C" void kernel_launch(void* const* d_in, const int* in_sizes, int n_in,
                              void* d_out, int out_size, void* d_ws, size_t ws_size,
                              hipStream_t stream) {
    const float* x     = (const float*)d_in[0];
    const float* Wt    = (const float*)d_in[1];
    const float* gamma = (const float*)d_in[2];
    const float* beta  = (const float*)d_in[3];
    float* out = (float*)d_out;

    char* ws = (char*)d_ws;
    U2* xbp = (U2*)ws;                                              // 1,722,368 B
    U2* wb  = (U2*)(ws + 1722368);                                  // 18,432 B
    unsigned long long* accum = (unsigned long long*)(ws + 1740800);// 32,768 B
    float2* ss = (float2*)(ws + 1773568);                           // 1,024 B
    unsigned short* rb = (unsigned short*)(ws + 1774592);           // 25,690,112 B

    hipLaunchKernelGGL(pack_x_k, dim3(NPIX / 4), dim3(256), 0, stream, x, xbp);
    hipLaunchKernelGGL(pack_w_k, dim3(9),        dim3(128), 0, stream, Wt, wb, accum, xbp);
    hipLaunchKernelGGL(conv_stats_k, dim3(HP, BB), dim3(256), 0, stream, xbp, wb, accum, rb);
    hipLaunchKernelGGL(finalize_k, dim3(1), dim3(128), 0, stream, accum, gamma, beta, ss);
    hipLaunchKernelGGL(out_stream_k, dim3(NPIX * CH / 4 / 256), dim3(256), 0, stream,
                       rb, (const float2*)ss, x, out);
}

// Round 10
// 66.779 us; speedup vs baseline: 1.8218x; 1.2118x over previous
//
#include <hip/hip_runtime.h>

#define CH    128
#define HH    56
#define WW    56
#define BB    32
#define NPIX  (BB * HH * WW)   // 100352
#define NSLOT 16

// ---------- MFMA-path geometry ----------
#define XROW   7424            // 58 cols * 128 ci, bytes per padded row
#define XBATCH 430592          // 58 rows * XROW
#define LDSROW 8448            // 66 px * 128 B
#define SWZ(pl, ci) ((ci) ^ (((pl) & 7) << 4))

// ---------- fallback (R9) geometry ----------
#define PW    58
#define PROW  (PW * PW)
#define HP    28

typedef int   i32x4  __attribute__((ext_vector_type(4)));
typedef int   i32x16 __attribute__((ext_vector_type(16)));

struct alignas(16) U2 { unsigned long long x, y; };

// =====================================================================
// ============================ MFMA PATH ==============================
// =====================================================================

__device__ __forceinline__ void mfma_i8(i32x16& acc, i32x4 a, i32x4 b) {
    asm("v_mfma_i32_32x32x32_i8 %0, %1, %2, %0" : "+v"(acc) : "v"(a), "v"(b));
}

// prep: xi8 interior + border zeros + wfrag (B pre-transpose) + accum zero
__global__ __launch_bounds__(256) void prep_k(const float* __restrict__ x,
                                              const float* __restrict__ Wt,
                                              signed char* __restrict__ xi8,
                                              signed char* __restrict__ wfrag,
                                              unsigned long long* __restrict__ accum) {
    int bx = blockIdx.x, tid = threadIdx.x;
    if (bx < 12544) {                       // interior signs: one float4 -> 4 int8
        int t = bx * 256 + tid;             // < 3,211,264
        int p = t >> 5;
        int ci0 = (t & 31) * 4;
        int w = p % WW;
        int t2 = p / WW;
        int h = t2 % HH;
        int b = t2 / HH;
        float4 v = ((const float4*)x)[t];
        unsigned o = (v.x >= 0.f ? 0x01u : 0xFFu)
                   | ((v.y >= 0.f ? 0x01u : 0xFFu) << 8)
                   | ((v.z >= 0.f ? 0x01u : 0xFFu) << 16)
                   | ((v.w >= 0.f ? 0x01u : 0xFFu) << 24);
        *(unsigned*)(xi8 + (size_t)b * XBATCH + (size_t)(h + 1) * XROW + (w + 1) * 128 + ci0) = o;
    } else if (bx < 12772) {                // border zeros: 58368 16B chunks
        int c = (bx - 12544) * 256 + tid;
        int cell = c >> 3, q = c & 7;
        int b = cell / 228, e = cell % 228;
        int row, col;
        if (e < 58)       { row = 0;       col = e; }
        else if (e < 116) { row = 57;      col = e - 58; }
        else if (e < 172) { row = e - 115; col = 0; }
        else              { row = e - 171; col = 57; }
        i32x4 z = {0, 0, 0, 0};
        *(i32x4*)(xi8 + (size_t)b * XBATCH + (size_t)row * XROW + col * 128 + q * 16) = z;
    } else if (bx < 12808) {                // wfrag: [n32][q=36][lane][16B]
        int i = (bx - 12772) * 256 + tid;   // < 9216
        int n = i / 2304;
        int r = i % 2304;
        int q = r / 64;
        int L = r % 64;
        int tap = q >> 2, kk = q & 3;
        int co = 32 * n + (L & 31);
        int kbase = 32 * kk + (L >> 5) * 16;
        i32x4 o;
        #pragma unroll
        for (int d = 0; d < 4; ++d) {
            unsigned u = 0;
            #pragma unroll
            for (int by = 0; by < 4; ++by) {
                int ci = kbase + 4 * d + by;
                unsigned s = (Wt[((size_t)tap * 128 + ci) * 128 + co] >= 0.f) ? 0x01u : 0xFFu;
                u |= s << (8 * by);
            }
            o[d] = (int)u;
        }
        *(i32x4*)(wfrag + (size_t)i * 16) = o;
    } else {                                // accum zero
        for (int k = tid; k < NSLOT * 256; k += 256) accum[k] = 0ull;
    }
}

// gemm: block = (padded row ph=bx+1, batch b). 8 waves = 4 col-tiles x 2 M-halves.
__global__ __launch_bounds__(512) void gemm_k(const signed char* __restrict__ xi8,
                                              const signed char* __restrict__ wfrag,
                                              unsigned long long* __restrict__ accum,
                                              unsigned short* __restrict__ rb) {
    __shared__ alignas(16) char sm[3 * LDSROW];   // 25344 B, swizzled
    int ph = blockIdx.x + 1;   // 1..56
    int b  = blockIdx.y;

    // stage rows ph-1..ph+1 (cols 0..57) into LDS pixels 1..58
    for (int c = threadIdx.x; c < 1392; c += 512) {
        int rr = c / 464;
        int off = (c % 464) * 16;
        int p = off >> 7, ci0 = off & 127;
        i32x4 v = *(const i32x4*)(xi8 + (size_t)b * XBATCH + (size_t)(ph - 1 + rr) * XROW + off);
        int pl = p + 1;
        *(i32x4*)(sm + rr * LDSROW + pl * 128 + SWZ(pl, ci0)) = v;
    }
    // guard pixels 0, 59..65 = zero
    for (int c = threadIdx.x; c < 192; c += 512) {
        int rr = c / 64, g = c % 64;
        int gp = g >> 3, ci0 = (g & 7) * 16;
        int pl = (gp == 0) ? 0 : (58 + gp);
        i32x4 z = {0, 0, 0, 0};
        *(i32x4*)(sm + rr * LDSROW + pl * 128 + SWZ(pl, ci0)) = z;
    }
    __syncthreads();

    int L = threadIdx.x & 63, w = threadIdx.x >> 6;
    int n32 = w & 3, sh = w >> 2;
    int l31 = L & 31, hi = L >> 5;

    // A-read byte offsets (dh folded as compile-time term)
    int aoff[3][4];
    #pragma unroll
    for (int dw = 0; dw < 3; ++dw) {
        int pld = l31 + dw;
        int pl = 32 * sh + pld;
        #pragma unroll
        for (int kk = 0; kk < 4; ++kk)
            aoff[dw][kk] = pl * 128 + ((32 * kk + 16 * hi) ^ ((pld & 7) << 4));
    }

    const i32x4* bfp = (const i32x4*)wfrag + (size_t)n32 * 36 * 64;
    i32x16 acc = {};

    #pragma unroll
    for (int pass = 0; pass < 2; ++pass) {
        i32x4 bfr[18];
        #pragma unroll
        for (int j = 0; j < 18; ++j) bfr[j] = bfp[(pass * 18 + j) * 64 + L];
        #pragma unroll
        for (int j = 0; j < 18; ++j) {
            int q = pass * 18 + j;
            int tap = q >> 2, kk = q & 3;
            int dh = tap / 3, dw = tap % 3;
            i32x4 a = *(const i32x4*)(sm + dh * LDSROW + aoff[dw][kk]);
            mfma_i8(acc, a, bfr[j]);
        }
    }
    // MFMA -> VALU hazard fence, dependent on acc so it can't be hoisted
    asm volatile("s_nop 7\n\ts_nop 7\n\ts_nop 7" : "+v"(acc));

    int co = 32 * n32 + l31;
    unsigned s1 = 0, s2 = 0;
    size_t rbase = (((size_t)b * HH + (ph - 1)) * WW) * CH + co;   // + (pw-1)*CH
    #pragma unroll
    for (int reg = 0; reg < 16; ++reg) {
        int pw = 32 * sh + (reg & 3) + 8 * (reg >> 2) + 4 * hi;
        int y = acc[reg];
        int r = y > 0 ? y : 0;
        if (pw >= 1 && pw <= WW) {
            s1 += (unsigned)r;
            s2 += (unsigned)__mul24(r, r);
            rb[rbase + (size_t)(pw - 1) * CH] = (unsigned short)r;
        }
    }
    s1 += __shfl_xor(s1, 32);
    s2 += __shfl_xor(s2, 32);
    if (hi == 0) {
        int slot = (blockIdx.x + blockIdx.y * HH) & (NSLOT - 1);
        atomicAdd(&accum[slot * 256 + co],       (unsigned long long)s1);
        atomicAdd(&accum[slot * 256 + 128 + co], (unsigned long long)s2);
    }
}

// =====================================================================
// ======================= FALLBACK (R9) PATH ==========================
// =====================================================================

__device__ __forceinline__ int corrv(U2 w) {
    return CH - 2 * (int)(__popcll(w.x) + __popcll(w.y));
}
__device__ __forceinline__ unsigned xp0(unsigned long long a, unsigned long long w) {
    unsigned acc, t0, t1;
    asm("v_xor_b32 %1, %3, %5\n\tv_xor_b32 %2, %4, %6\n\t"
        "v_bcnt_u32_b32 %0, %1, 0\n\tv_bcnt_u32_b32 %0, %2, %0"
        : "=&v"(acc), "=&v"(t0), "=&v"(t1)
        : "v"((unsigned)a), "v"((unsigned)(a >> 32)), "v"((unsigned)w), "v"((unsigned)(w >> 32)));
    return acc;
}
__device__ __forceinline__ unsigned xp(unsigned acc, unsigned long long a, unsigned long long w) {
    unsigned t0, t1;
    asm("v_xor_b32 %1, %3, %5\n\tv_xor_b32 %2, %4, %6\n\t"
        "v_bcnt_u32_b32 %0, %1, %0\n\tv_bcnt_u32_b32 %0, %2, %0"
        : "+v"(acc), "=&v"(t0), "=&v"(t1)
        : "v"((unsigned)a), "v"((unsigned)(a >> 32)), "v"((unsigned)w), "v"((unsigned)(w >> 32)));
    return acc;
}
__device__ __forceinline__ unsigned row_mis(const U2& A, const U2& B, const U2& C,
                                            const U2& w0, const U2& w1, const U2& w2) {
    unsigned m = xp0(A.x, w0.x);
    m = xp(m, A.y, w0.y); m = xp(m, B.x, w1.x); m = xp(m, B.y, w1.y);
    m = xp(m, C.x, w2.x); m = xp(m, C.y, w2.y);
    return m;
}

__global__ __launch_bounds__(256) void pack_x_k(const float* __restrict__ x, U2* __restrict__ xbp) {
    int wave = threadIdx.x >> 6, lane = threadIdx.x & 63;
    int p = blockIdx.x * 4 + wave;
    const float2* px = (const float2*)(x + (size_t)p * CH);
    float2 v = px[lane];
    unsigned long long b0 = __ballot(v.x >= 0.0f);
    unsigned long long b1 = __ballot(v.y >= 0.0f);
    if (lane == 0) {
        int w = p % WW; int t = p / WW; int h = t % HH; int b = t / HH;
        U2 o; o.x = b0; o.y = b1;
        xbp[(size_t)b * PROW + (size_t)(h + 1) * PW + (w + 1)] = o;
    }
}

__global__ __launch_bounds__(128) void pack_w_k(const float* __restrict__ Wt, U2* __restrict__ wb,
                                                unsigned long long* __restrict__ accum,
                                                U2* __restrict__ xbp) {
    int tap = blockIdx.x, co = threadIdx.x;
    int gtid = tap * 128 + co;
    for (int k = gtid; k < NSLOT * 256; k += 9 * 128) accum[k] = 0ull;
    U2 z; z.x = 0ull; z.y = 0ull;
    for (int k = gtid; k < BB * 228; k += 9 * 128) {
        int bb = k / 228, e = k % 228;
        int row, col;
        if (e < 58)       { row = 0;       col = e; }
        else if (e < 116) { row = 57;      col = e - 58; }
        else if (e < 172) { row = e - 115; col = 0; }
        else              { row = e - 171; col = 57; }
        xbp[(size_t)bb * PROW + (size_t)row * PW + col] = z;
    }
    const float* base = Wt + (size_t)tap * CH * CH + co;
    unsigned long long b0 = 0, b1 = 0;
    #pragma unroll 4
    for (int ci = 0; ci < 64; ++ci) {
        if (base[(size_t)(2 * ci)     * CH] >= 0.0f) b0 |= 1ull << ci;
        if (base[(size_t)(2 * ci + 1) * CH] >= 0.0f) b1 |= 1ull << ci;
    }
    wb[tap * CH + co].x = b0;
    wb[tap * CH + co].y = b1;
}

__global__ __launch_bounds__(256) void conv_stats_k(const U2* __restrict__ xbp,
                                                    const U2* __restrict__ wbg,
                                                    unsigned long long* __restrict__ accum,
                                                    unsigned short* __restrict__ rb) {
    int hp = blockIdx.x, b = blockIdx.y;
    int tid = threadIdx.x;
    int c = tid & (CH - 1), g = tid >> 7;
    int rowA = 2 * hp;
    U2 wk[9]; int co[9];
    #pragma unroll
    for (int t = 0; t < 9; ++t) { wk[t] = wbg[t * CH + c]; co[t] = corrv(wk[t]); }
    bool e0 = (hp == 0), e2 = (hp == HP - 1);
    int baseA = 9 * CH, baseB = 9 * CH;
    if (e0) baseA -= co[0] + co[1] + co[2];
    if (e2) baseB -= co[6] + co[7] + co[8];
    int ccol0A = co[3] + (!e0 ? co[0] : 0) + co[6];
    int ccol2A = co[5] + (!e0 ? co[2] : 0) + co[8];
    int ccol0B = co[3] + co[0] + (!e2 ? co[6] : 0);
    int ccol2B = co[5] + co[2] + (!e2 ? co[8] : 0);
    int w0 = g * 28;
    const U2* q0 = xbp + (size_t)b * PROW + (size_t)rowA * PW + w0;
    const U2* q1 = q0 + PW; const U2* q2 = q1 + PW; const U2* q3 = q2 + PW;
    U2 A0 = q0[0], A1 = q1[0], A2 = q2[0], A3 = q3[0];
    U2 B0 = q0[1], B1 = q1[1], B2 = q2[1], B3 = q3[1];
    unsigned s1 = 0, s2 = 0;
    unsigned short* routA = rb + ((((size_t)b * HH + rowA) * WW) + w0) * CH + c;
    unsigned short* routB = routA + (size_t)WW * CH;
    #pragma unroll 14
    for (int i = 0; i < 28; ++i) {
        U2 C0 = q0[i + 2], C1 = q1[i + 2], C2 = q2[i + 2], C3 = q3[i + 2];
        unsigned mA0 = row_mis(A0, B0, C0, wk[0], wk[1], wk[2]);
        unsigned mA1 = row_mis(A1, B1, C1, wk[3], wk[4], wk[5]);
        unsigned mA2 = row_mis(A2, B2, C2, wk[6], wk[7], wk[8]);
        unsigned mB0 = row_mis(A1, B1, C1, wk[0], wk[1], wk[2]);
        unsigned mB1 = row_mis(A2, B2, C2, wk[3], wk[4], wk[5]);
        unsigned mB2 = row_mis(A3, B3, C3, wk[6], wk[7], wk[8]);
        int yA = baseA - 2 * (int)(mA0 + mA1 + mA2);
        int yB = baseB - 2 * (int)(mB0 + mB1 + mB2);
        if (i == 0  && g == 0) { yA -= ccol0A; yB -= ccol0B; }
        if (i == 27 && g == 1) { yA -= ccol2A; yB -= ccol2B; }
        int ra = yA > 0 ? yA : 0, rv = yB > 0 ? yB : 0;
        s1 += (unsigned)(ra + rv);
        s2 += (unsigned)__mul24(ra, ra) + (unsigned)__mul24(rv, rv);
        routA[(size_t)i * CH] = (unsigned short)ra;
        routB[(size_t)i * CH] = (unsigned short)rv;
        A0 = B0; A1 = B1; A2 = B2; A3 = B3;
        B0 = C0; B1 = C1; B2 = C2; B3 = C3;
    }
    int slot = (hp + b * HP) & (NSLOT - 1);
    atomicAdd(&accum[slot * 256 + c],       (unsigned long long)s1);
    atomicAdd(&accum[slot * 256 + 128 + c], (unsigned long long)s2);
}

// =====================================================================
// ========================= SHARED TAIL ===============================
// =====================================================================

__global__ __launch_bounds__(128) void finalize_k(const unsigned long long* __restrict__ accum,
                                                  const float* __restrict__ gamma,
                                                  const float* __restrict__ beta,
                                                  float2* __restrict__ ss) {
    int c = threadIdx.x;
    unsigned long long s1 = 0, s2 = 0;
    #pragma unroll
    for (int s = 0; s < NSLOT; ++s) {
        s1 += accum[s * 256 + c];
        s2 += accum[s * 256 + 128 + c];
    }
    double N    = (double)NPIX;
    double mean = (double)s1 / N;
    double var  = (double)s2 / N - mean * mean;
    double rstd = 1.0 / sqrt(var + 1e-3);
    double sc   = (double)gamma[c] * rstd;
    float2 v;
    v.x = (float)sc;
    v.y = (float)((double)beta[c] - mean * sc);
    ss[c] = v;
}

__global__ __launch_bounds__(256) void out_stream_k(const unsigned short* __restrict__ rb,
                                                    const float2* __restrict__ ss,
                                                    const float* __restrict__ x,
                                                    float* __restrict__ out) {
    int idx4 = blockIdx.x * 256 + threadIdx.x;
    int c4 = idx4 & (CH / 4 - 1);
    ushort4 r = ((const ushort4*)rb)[idx4];
    float4 xv = ((const float4*)x)[idx4];
    float2 s0 = ss[c4 * 4 + 0], s1 = ss[c4 * 4 + 1];
    float2 s2 = ss[c4 * 4 + 2], s3 = ss[c4 * 4 + 3];
    float4 o;
    o.x = fmaf((float)r.x, s0.x, s0.y + xv.x);
    o.y = fmaf((float)r.y, s1.x, s1.y + xv.y);
    o.z = fmaf((float)r.z, s2.x, s2.y + xv.z);
    o.w = fmaf((float)r.w, s3.x, s3.y + xv.w);
    ((float4*)out)[idx4] = o;
}

extern "C" void kernel_launch(void* const* d_in, const int* in_sizes, int n_in,
                              void* d_out, int out_size, void* d_ws, size_t ws_size,
                              hipStream_t stream) {
    const float* x     = (const float*)d_in[0];
    const float* Wt    = (const float*)d_in[1];
    const float* gamma = (const float*)d_in[2];
    const float* beta  = (const float*)d_in[3];
    float* out = (float*)d_out;
    char* ws = (char*)d_ws;

    const size_t WS_MFMA = 39650304ull;
    if (ws_size >= WS_MFMA) {
        signed char* xi8   = (signed char*)ws;                            // 13,778,944
        signed char* wfrag = (signed char*)(ws + 13778944);               //    147,456
        unsigned long long* accum = (unsigned long long*)(ws + 13926400); //     32,768
        float2* ss = (float2*)(ws + 13959168);                            //      1,024
        unsigned short* rb = (unsigned short*)(ws + 13960192);            // 25,690,112

        hipLaunchKernelGGL(prep_k, dim3(12809), dim3(256), 0, stream, x, Wt, xi8, wfrag, accum);
        hipLaunchKernelGGL(gemm_k, dim3(HH, BB), dim3(512), 0, stream, xi8, wfrag, accum, rb);
        hipLaunchKernelGGL(finalize_k, dim3(1), dim3(128), 0, stream, accum, gamma, beta, ss);
        hipLaunchKernelGGL(out_stream_k, dim3(NPIX * CH / 4 / 256), dim3(256), 0, stream,
                           rb, (const float2*)ss, x, out);
    } else {
        U2* xbp = (U2*)ws;                                                // 1,722,368
        U2* wb  = (U2*)(ws + 1722368);                                    //    18,432
        unsigned long long* accum = (unsigned long long*)(ws + 1740800);  //    32,768
        float2* ss = (float2*)(ws + 1773568);                             //     1,024
        unsigned short* rb = (unsigned short*)(ws + 1774592);             // 25,690,112

        hipLaunchKernelGGL(pack_x_k, dim3(NPIX / 4), dim3(256), 0, stream, x, xbp);
        hipLaunchKernelGGL(pack_w_k, dim3(9), dim3(128), 0, stream, Wt, wb, accum, xbp);
        hipLaunchKernelGGL(conv_stats_k, dim3(HP, BB), dim3(256), 0, stream, xbp, wb, accum, rb);
        hipLaunchKernelGGL(finalize_k, dim3(1), dim3(128), 0, stream, accum, gamma, beta, ss);
        hipLaunchKernelGGL(out_stream_k, dim3(NPIX * CH / 4 / 256), dim3(256), 0, stream,
                           rb, (const float2*)ss, x, out);
    }
}